// Round 1
// baseline (1220.994 us; speedup 1.0000x reference)
//
#include <hip/hip_runtime.h>

// UnionRGCNLayer: algebraically restructured RGCN layer.
// agg[v] = (sum_{e: dst=v} (t[src_e] + emb_rel[type_e]) + deg[v]*b_hp) @ Wn
// t[u] = [h[u] | pos[u]] @ W_hp
// out_node = relu(norm*agg + h @ (deg>0 ? Lw : Ew))
// out_pos  = relu(pos + pos @ (deg>0 ? Lwp : Ewp))

#define DD 128
#define PP 3

// ---------------- Kernel 1: t = [h | pos] @ W_hp  ([N,131] @ [131,128]) ----------------
__global__ __launch_bounds__(256) void k_t(const float* __restrict__ h,
                                           const float* __restrict__ pos,
                                           const float* __restrict__ Whp,
                                           float* __restrict__ t, int N) {
    __shared__ __align__(16) float Xs[64][33];
    __shared__ __align__(16) float Ws[32][128];
    const int tid = threadIdx.x;
    const int rbase = blockIdx.x * 64;
    const int cg = tid & 31;   // cols 4*cg .. 4*cg+3
    const int rg = tid >> 5;   // rows rg*8 .. rg*8+7
    float4 acc[8];
#pragma unroll
    for (int i = 0; i < 8; i++) acc[i] = make_float4(0.f, 0.f, 0.f, 0.f);

    for (int kbase = 0; kbase < 131; kbase += 32) {
        const int KC = min(32, 131 - kbase);
        // stage W chunk: KC x 128
        for (int idx = tid; idx < KC * 32; idx += 256) {
            int k = idx >> 5, cv = idx & 31;
            *reinterpret_cast<float4*>(&Ws[k][cv * 4]) =
                *reinterpret_cast<const float4*>(Whp + (size_t)(kbase + k) * 128 + cv * 4);
        }
        // stage X chunk
        if (kbase < 128) {
            for (int idx = tid; idx < 64 * 8; idx += 256) {
                int r = idx >> 3, kv = idx & 7;
                int row = rbase + r;
                float4 x = make_float4(0.f, 0.f, 0.f, 0.f);
                if (row < N)
                    x = *reinterpret_cast<const float4*>(h + (size_t)row * 128 + kbase + kv * 4);
                Xs[r][kv * 4 + 0] = x.x; Xs[r][kv * 4 + 1] = x.y;
                Xs[r][kv * 4 + 2] = x.z; Xs[r][kv * 4 + 3] = x.w;
            }
        } else {
            for (int idx = tid; idx < 64 * 3; idx += 256) {
                int r = idx / 3, j = idx % 3;
                int row = rbase + r;
                Xs[r][j] = (row < N) ? pos[(size_t)row * 3 + j] : 0.f;
            }
        }
        __syncthreads();
        for (int k = 0; k < KC; k++) {
            float4 w = *reinterpret_cast<const float4*>(&Ws[k][cg * 4]);
#pragma unroll
            for (int i = 0; i < 8; i++) {
                float x = Xs[rg * 8 + i][k];
                acc[i].x += x * w.x; acc[i].y += x * w.y;
                acc[i].z += x * w.z; acc[i].w += x * w.w;
            }
        }
        __syncthreads();
    }
#pragma unroll
    for (int i = 0; i < 8; i++) {
        int row = rbase + rg * 8 + i;
        if (row < N)
            *reinterpret_cast<float4*>(t + (size_t)row * 128 + cg * 4) = acc[i];
    }
}

// ---------------- Kernel 2: edge scatter: acc[dst] += t[src] + emb_rel[type]; deg[dst]++ ----------------
__global__ __launch_bounds__(256) void k_edge(const float* __restrict__ t,
                                              const float* __restrict__ emb_rel,
                                              const int* __restrict__ src,
                                              const int* __restrict__ dst,
                                              const int* __restrict__ typ,
                                              float* __restrict__ acc,
                                              int* __restrict__ deg, int E) {
    const int lane = threadIdx.x & 31;
    const int eg = (blockIdx.x * blockDim.x + threadIdx.x) >> 5;
    const int stride = (gridDim.x * blockDim.x) >> 5;
    for (int e = eg; e < E; e += stride) {
        int s = src[e], d = dst[e], r = typ[e];
        float4 v = *reinterpret_cast<const float4*>(t + (size_t)s * 128 + lane * 4);
        float4 u = *reinterpret_cast<const float4*>(emb_rel + (size_t)r * 128 + lane * 4);
        float* a = acc + (size_t)d * 128 + lane * 4;
        atomicAdd(a + 0, v.x + u.x);
        atomicAdd(a + 1, v.y + u.y);
        atomicAdd(a + 2, v.z + u.z);
        atomicAdd(a + 3, v.w + u.w);
        if (lane == 0) atomicAdd(deg + d, 1);
    }
}

// ---------------- Kernel 3: fused final K=384 GEMM + pos path ----------------
// out_node = relu([norm*(acc+deg*b) | f*h | (1-f)*h] @ [Wn; Lw; Ew]),  f = deg>0
__global__ __launch_bounds__(256) void k_final(const float* __restrict__ h,
                                               const float* __restrict__ pos,
                                               const float* __restrict__ nrm,
                                               const float* __restrict__ bhp,
                                               const float* __restrict__ Wn,
                                               const float* __restrict__ Lw,
                                               const float* __restrict__ Ew,
                                               const float* __restrict__ Lwp,
                                               const float* __restrict__ Ewp,
                                               const float* __restrict__ accbuf,
                                               const int* __restrict__ deg,
                                               float* __restrict__ out, int N) {
    __shared__ __align__(16) float Xs[64][33];
    __shared__ __align__(16) float Ws[32][128];
    __shared__ float normf[64];
    __shared__ float degf[64];
    __shared__ int flag[64];
    __shared__ __align__(16) float bs[128];
    const int tid = threadIdx.x;
    const int rbase = blockIdx.x * 64;
    if (tid < 64) {
        int row = rbase + tid;
        int dg = (row < N) ? deg[row] : 0;
        degf[tid] = (float)dg;
        flag[tid] = (dg > 0) ? 1 : 0;
        normf[tid] = (row < N) ? nrm[row] : 0.f;
    }
    if (tid >= 64 && tid < 192) bs[tid - 64] = bhp[tid - 64];
    __syncthreads();

    const int cg = tid & 31;
    const int rg = tid >> 5;
    float4 acc[8];
#pragma unroll
    for (int i = 0; i < 8; i++) acc[i] = make_float4(0.f, 0.f, 0.f, 0.f);

    for (int kbase = 0; kbase < 384; kbase += 32) {
        const int part = kbase >> 7;  // 0: Wn/acc-part, 1: Lw/h(f), 2: Ew/h(1-f)
        const int klocal = kbase & 127;
        const float* Wp = (part == 0) ? (Wn + (size_t)klocal * 128)
                        : (part == 1) ? (Lw + (size_t)klocal * 128)
                                      : (Ew + (size_t)klocal * 128);
        for (int idx = tid; idx < 1024; idx += 256) {
            int k = idx >> 5, cv = idx & 31;
            *reinterpret_cast<float4*>(&Ws[k][cv * 4]) =
                *reinterpret_cast<const float4*>(Wp + (size_t)k * 128 + cv * 4);
        }
        for (int idx = tid; idx < 512; idx += 256) {
            int r = idx >> 3, kv = idx & 7;
            int row = rbase + r;
            int kk = klocal + kv * 4;
            float4 x = make_float4(0.f, 0.f, 0.f, 0.f);
            if (row < N) {
                if (part == 0) {
                    float4 a4 = *reinterpret_cast<const float4*>(accbuf + (size_t)row * 128 + kk);
                    float4 b4 = *reinterpret_cast<const float4*>(&bs[kk]);
                    float dgf = degf[r], nf = normf[r];
                    x.x = nf * (a4.x + dgf * b4.x);
                    x.y = nf * (a4.y + dgf * b4.y);
                    x.z = nf * (a4.z + dgf * b4.z);
                    x.w = nf * (a4.w + dgf * b4.w);
                } else {
                    bool f = (flag[r] != 0);
                    bool keep = (part == 1) ? f : !f;
                    if (keep)
                        x = *reinterpret_cast<const float4*>(h + (size_t)row * 128 + kk);
                }
            }
            Xs[r][kv * 4 + 0] = x.x; Xs[r][kv * 4 + 1] = x.y;
            Xs[r][kv * 4 + 2] = x.z; Xs[r][kv * 4 + 3] = x.w;
        }
        __syncthreads();
        for (int k = 0; k < 32; k++) {
            float4 w = *reinterpret_cast<const float4*>(&Ws[k][cg * 4]);
#pragma unroll
            for (int i = 0; i < 8; i++) {
                float x = Xs[rg * 8 + i][k];
                acc[i].x += x * w.x; acc[i].y += x * w.y;
                acc[i].z += x * w.z; acc[i].w += x * w.w;
            }
        }
        __syncthreads();
    }
#pragma unroll
    for (int i = 0; i < 8; i++) {
        int row = rbase + rg * 8 + i;
        if (row < N) {
            float4 y = acc[i];
            y.x = fmaxf(y.x, 0.f); y.y = fmaxf(y.y, 0.f);
            y.z = fmaxf(y.z, 0.f); y.w = fmaxf(y.w, 0.f);
            *reinterpret_cast<float4*>(out + (size_t)row * 128 + cg * 4) = y;
        }
    }
    // pos path: pos_out = relu(pos + pos @ (f ? Lwp : Ewp)), 3x3
    if (tid < 64) {
        int row = rbase + tid;
        if (row < N) {
            float p0 = pos[(size_t)row * 3 + 0];
            float p1 = pos[(size_t)row * 3 + 1];
            float p2 = pos[(size_t)row * 3 + 2];
            const float* M = flag[tid] ? Lwp : Ewp;
            float o0 = p0 + (p0 * M[0] + p1 * M[3] + p2 * M[6]);
            float o1 = p1 + (p0 * M[1] + p1 * M[4] + p2 * M[7]);
            float o2 = p2 + (p0 * M[2] + p1 * M[5] + p2 * M[8]);
            size_t base = (size_t)N * 128 + (size_t)row * 3;
            out[base + 0] = fmaxf(o0, 0.f);
            out[base + 1] = fmaxf(o1, 0.f);
            out[base + 2] = fmaxf(o2, 0.f);
        }
    }
}

extern "C" void kernel_launch(void* const* d_in, const int* in_sizes, int n_in,
                              void* d_out, int out_size, void* d_ws, size_t ws_size,
                              hipStream_t stream) {
    const float* h    = (const float*)d_in[0];
    const float* pos  = (const float*)d_in[1];
    const float* nrm  = (const float*)d_in[2];
    const float* emb  = (const float*)d_in[3];
    const float* Whp  = (const float*)d_in[4];
    const float* bhp  = (const float*)d_in[5];
    const float* Wn   = (const float*)d_in[6];
    const float* Lw   = (const float*)d_in[7];
    const float* Ew   = (const float*)d_in[8];
    const float* Lwp  = (const float*)d_in[9];
    const float* Ewp  = (const float*)d_in[10];
    const int* esrc   = (const int*)d_in[11];
    const int* edst   = (const int*)d_in[12];
    const int* etyp   = (const int*)d_in[13];

    const int N = in_sizes[2];   // norm has N elements
    const int E = in_sizes[11];  // edge_src

    float* out  = (float*)d_out;
    float* t    = (float*)d_ws;                                   // N*128 floats
    int*   deg  = (int*)((char*)d_ws + (size_t)N * 128 * 4);      // N ints
    float* accb = out;                                            // acc lives in out's node region

    // zero acc + deg (graph-capturable)
    hipMemsetAsync(accb, 0, (size_t)N * 128 * 4, stream);
    hipMemsetAsync(deg, 0, (size_t)N * 4, stream);

    const int nblk = (N + 63) / 64;
    k_t<<<nblk, 256, 0, stream>>>(h, pos, Whp, t, N);
    k_edge<<<4096, 256, 0, stream>>>(t, emb, esrc, edst, etyp, accb, deg, E);
    k_final<<<nblk, 256, 0, stream>>>(h, pos, nrm, bhp, Wn, Lw, Ew, Lwp, Ewp,
                                      accb, deg, out, N);
}

// Round 2
// 307.049 us; speedup vs baseline: 3.9766x; 3.9766x over previous
//
#include <hip/hip_runtime.h>

// UnionRGCNLayer restructured:
//   t[u]   = [h[u] | pos[u]] @ W_hp                       (node-level, not per-edge)
//   acc[v] = sum_{e: dst=v} (t[src_e] + emb_rel[type_e])  (CSR gather, no float atomics)
//   out_node = relu([norm*(acc+deg*b) | f*h | (1-f)*h] @ [Wn; Lw; Ew]),  f = deg>0
//   out_pos  = relu(pos + pos @ (f ? Lwp : Ewp))

// ---------------- Kernel 1: t = [h | pos] @ W_hp  ([N,131] @ [131,128]) ----------------
__global__ __launch_bounds__(256) void k_t(const float* __restrict__ h,
                                           const float* __restrict__ pos,
                                           const float* __restrict__ Whp,
                                           float* __restrict__ t, int N) {
    __shared__ __align__(16) float Xs[64][33];
    __shared__ __align__(16) float Ws[32][128];
    const int tid = threadIdx.x;
    const int rbase = blockIdx.x * 64;
    const int cg = tid & 31;
    const int rg = tid >> 5;
    float4 acc[8];
#pragma unroll
    for (int i = 0; i < 8; i++) acc[i] = make_float4(0.f, 0.f, 0.f, 0.f);

    for (int kbase = 0; kbase < 131; kbase += 32) {
        const int KC = min(32, 131 - kbase);
        for (int idx = tid; idx < KC * 32; idx += 256) {
            int k = idx >> 5, cv = idx & 31;
            *reinterpret_cast<float4*>(&Ws[k][cv * 4]) =
                *reinterpret_cast<const float4*>(Whp + (size_t)(kbase + k) * 128 + cv * 4);
        }
        if (kbase < 128) {
            for (int idx = tid; idx < 64 * 8; idx += 256) {
                int r = idx >> 3, kv = idx & 7;
                int row = rbase + r;
                float4 x = make_float4(0.f, 0.f, 0.f, 0.f);
                if (row < N)
                    x = *reinterpret_cast<const float4*>(h + (size_t)row * 128 + kbase + kv * 4);
                Xs[r][kv * 4 + 0] = x.x; Xs[r][kv * 4 + 1] = x.y;
                Xs[r][kv * 4 + 2] = x.z; Xs[r][kv * 4 + 3] = x.w;
            }
        } else {
            for (int idx = tid; idx < 64 * 3; idx += 256) {
                int r = idx / 3, j = idx % 3;
                int row = rbase + r;
                Xs[r][j] = (row < N) ? pos[(size_t)row * 3 + j] : 0.f;
            }
        }
        __syncthreads();
        for (int k = 0; k < KC; k++) {
            float4 w = *reinterpret_cast<const float4*>(&Ws[k][cg * 4]);
#pragma unroll
            for (int i = 0; i < 8; i++) {
                float x = Xs[rg * 8 + i][k];
                acc[i].x += x * w.x; acc[i].y += x * w.y;
                acc[i].z += x * w.z; acc[i].w += x * w.w;
            }
        }
        __syncthreads();
    }
#pragma unroll
    for (int i = 0; i < 8; i++) {
        int row = rbase + rg * 8 + i;
        if (row < N)
            *reinterpret_cast<float4*>(t + (size_t)row * 128 + cg * 4) = acc[i];
    }
}

// ---------------- CSR build ----------------
__global__ __launch_bounds__(256) void k_hist(const int* __restrict__ dst,
                                              int* __restrict__ rp, int E) {
    int i = blockIdx.x * blockDim.x + threadIdx.x;
    int stride = gridDim.x * blockDim.x;
    for (int e = i; e < E; e += stride) atomicAdd(&rp[dst[e]], 1);
}

__global__ __launch_bounds__(1024) void k_scan(int* __restrict__ rp, int N) {
    __shared__ int part[1024];
    const int tid = threadIdx.x;
    const int chunk = (N + 1023) / 1024;
    const int beg = tid * chunk;
    const int end = min(beg + chunk, N);
    int s = 0;
    for (int i = beg; i < end; i++) s += rp[i];
    part[tid] = s;
    __syncthreads();
    for (int off = 1; off < 1024; off <<= 1) {
        int other = (tid >= off) ? part[tid - off] : 0;
        __syncthreads();
        part[tid] += other;
        __syncthreads();
    }
    int running = part[tid] - s;  // exclusive offset for this chunk
    for (int i = beg; i < end; i++) {
        int tmp = rp[i];
        rp[i] = running;
        running += tmp;
    }
}

// scatter: rp holds exclusive offsets; after this, rp[v] = end offset of v's list
__global__ __launch_bounds__(256) void k_scatter(const int* __restrict__ src,
                                                 const int* __restrict__ dst,
                                                 const int* __restrict__ typ,
                                                 int* __restrict__ rp,
                                                 unsigned* __restrict__ epack, int E) {
    int i = blockIdx.x * blockDim.x + threadIdx.x;
    int stride = gridDim.x * blockDim.x;
    for (int e = i; e < E; e += stride) {
        int d = dst[e];
        int pos = atomicAdd(&rp[d], 1);
        epack[pos] = (unsigned)src[e] | ((unsigned)typ[e] << 16);
    }
}

// ---------------- gather: acc[v] = sum over v's edges of t[src]+emb[type] ----------------
__global__ __launch_bounds__(256) void k_gather(const float* __restrict__ t,
                                                const float* __restrict__ emb,
                                                const unsigned* __restrict__ epack,
                                                const int* __restrict__ rp,
                                                float* __restrict__ acc, int N) {
    const int wid = (blockIdx.x * blockDim.x + threadIdx.x) >> 6;  // wave -> node
    const int lane = threadIdx.x & 63;
    if (wid >= N) return;
    const int start = wid ? rp[wid - 1] : 0;
    const int end = rp[wid];
    float2 a = make_float2(0.f, 0.f);
    for (int i = start; i < end; i++) {
        unsigned p = epack[i];
        int s = p & 0xffff;
        int r = p >> 16;
        float2 tv = *reinterpret_cast<const float2*>(t + (size_t)s * 128 + lane * 2);
        float2 ev = *reinterpret_cast<const float2*>(emb + (size_t)r * 128 + lane * 2);
        a.x += tv.x + ev.x;
        a.y += tv.y + ev.y;
    }
    *reinterpret_cast<float2*>(acc + (size_t)wid * 128 + lane * 2) = a;
}

// ---------------- legacy atomic scatter (ws fallback) ----------------
__global__ __launch_bounds__(256) void k_edge(const float* __restrict__ t,
                                              const float* __restrict__ emb_rel,
                                              const int* __restrict__ src,
                                              const int* __restrict__ dst,
                                              const int* __restrict__ typ,
                                              float* __restrict__ acc,
                                              int* __restrict__ deg, int E) {
    const int lane = threadIdx.x & 31;
    const int eg = (blockIdx.x * blockDim.x + threadIdx.x) >> 5;
    const int stride = (gridDim.x * blockDim.x) >> 5;
    for (int e = eg; e < E; e += stride) {
        int s = src[e], d = dst[e], r = typ[e];
        float4 v = *reinterpret_cast<const float4*>(t + (size_t)s * 128 + lane * 4);
        float4 u = *reinterpret_cast<const float4*>(emb_rel + (size_t)r * 128 + lane * 4);
        float* a = acc + (size_t)d * 128 + lane * 4;
        atomicAdd(a + 0, v.x + u.x);
        atomicAdd(a + 1, v.y + u.y);
        atomicAdd(a + 2, v.z + u.z);
        atomicAdd(a + 3, v.w + u.w);
        if (lane == 0) atomicAdd(deg + d, 1);
    }
}

// ---------------- final fused K=384 GEMM + pos path ----------------
__global__ __launch_bounds__(256) void k_final(const float* __restrict__ h,
                                               const float* __restrict__ pos,
                                               const float* __restrict__ nrm,
                                               const float* __restrict__ bhp,
                                               const float* __restrict__ Wn,
                                               const float* __restrict__ Lw,
                                               const float* __restrict__ Ew,
                                               const float* __restrict__ Lwp,
                                               const float* __restrict__ Ewp,
                                               const float* __restrict__ accbuf,
                                               const int* __restrict__ rp,
                                               const int* __restrict__ deg,
                                               float* __restrict__ out, int N) {
    __shared__ __align__(16) float Xs[64][33];
    __shared__ __align__(16) float Ws[32][128];
    __shared__ float normf[64];
    __shared__ float degf[64];
    __shared__ int flag[64];
    __shared__ __align__(16) float bs[128];
    const int tid = threadIdx.x;
    const int rbase = blockIdx.x * 64;
    if (tid < 64) {
        int row = rbase + tid;
        int dg = 0;
        if (row < N) {
            if (deg) dg = deg[row];
            else     dg = rp[row] - (row ? rp[row - 1] : 0);
        }
        degf[tid] = (float)dg;
        flag[tid] = (dg > 0) ? 1 : 0;
        normf[tid] = (row < N) ? nrm[row] : 0.f;
    }
    if (tid >= 64 && tid < 192) bs[tid - 64] = bhp[tid - 64];
    __syncthreads();

    const int cg = tid & 31;
    const int rg = tid >> 5;
    float4 acc[8];
#pragma unroll
    for (int i = 0; i < 8; i++) acc[i] = make_float4(0.f, 0.f, 0.f, 0.f);

    for (int kbase = 0; kbase < 384; kbase += 32) {
        const int part = kbase >> 7;  // 0: Wn/acc-part, 1: Lw/h(f), 2: Ew/h(1-f)
        const int klocal = kbase & 127;
        const float* Wp = (part == 0) ? (Wn + (size_t)klocal * 128)
                        : (part == 1) ? (Lw + (size_t)klocal * 128)
                                      : (Ew + (size_t)klocal * 128);
        for (int idx = tid; idx < 1024; idx += 256) {
            int k = idx >> 5, cv = idx & 31;
            *reinterpret_cast<float4*>(&Ws[k][cv * 4]) =
                *reinterpret_cast<const float4*>(Wp + (size_t)k * 128 + cv * 4);
        }
        for (int idx = tid; idx < 512; idx += 256) {
            int r = idx >> 3, kv = idx & 7;
            int row = rbase + r;
            int kk = klocal + kv * 4;
            float4 x = make_float4(0.f, 0.f, 0.f, 0.f);
            if (row < N) {
                if (part == 0) {
                    float4 a4 = *reinterpret_cast<const float4*>(accbuf + (size_t)row * 128 + kk);
                    float4 b4 = *reinterpret_cast<const float4*>(&bs[kk]);
                    float dgf = degf[r], nf = normf[r];
                    x.x = nf * (a4.x + dgf * b4.x);
                    x.y = nf * (a4.y + dgf * b4.y);
                    x.z = nf * (a4.z + dgf * b4.z);
                    x.w = nf * (a4.w + dgf * b4.w);
                } else {
                    bool f = (flag[r] != 0);
                    bool keep = (part == 1) ? f : !f;
                    if (keep)
                        x = *reinterpret_cast<const float4*>(h + (size_t)row * 128 + kk);
                }
            }
            Xs[r][kv * 4 + 0] = x.x; Xs[r][kv * 4 + 1] = x.y;
            Xs[r][kv * 4 + 2] = x.z; Xs[r][kv * 4 + 3] = x.w;
        }
        __syncthreads();
        for (int k = 0; k < 32; k++) {
            float4 w = *reinterpret_cast<const float4*>(&Ws[k][cg * 4]);
#pragma unroll
            for (int i = 0; i < 8; i++) {
                float x = Xs[rg * 8 + i][k];
                acc[i].x += x * w.x; acc[i].y += x * w.y;
                acc[i].z += x * w.z; acc[i].w += x * w.w;
            }
        }
        __syncthreads();
    }
#pragma unroll
    for (int i = 0; i < 8; i++) {
        int row = rbase + rg * 8 + i;
        if (row < N) {
            float4 y = acc[i];
            y.x = fmaxf(y.x, 0.f); y.y = fmaxf(y.y, 0.f);
            y.z = fmaxf(y.z, 0.f); y.w = fmaxf(y.w, 0.f);
            *reinterpret_cast<float4*>(out + (size_t)row * 128 + cg * 4) = y;
        }
    }
    if (tid < 64) {
        int row = rbase + tid;
        if (row < N) {
            float p0 = pos[(size_t)row * 3 + 0];
            float p1 = pos[(size_t)row * 3 + 1];
            float p2 = pos[(size_t)row * 3 + 2];
            const float* M = flag[tid] ? Lwp : Ewp;
            float o0 = p0 + (p0 * M[0] + p1 * M[3] + p2 * M[6]);
            float o1 = p1 + (p0 * M[1] + p1 * M[4] + p2 * M[7]);
            float o2 = p2 + (p0 * M[2] + p1 * M[5] + p2 * M[8]);
            size_t base = (size_t)N * 128 + (size_t)row * 3;
            out[base + 0] = fmaxf(o0, 0.f);
            out[base + 1] = fmaxf(o1, 0.f);
            out[base + 2] = fmaxf(o2, 0.f);
        }
    }
}

extern "C" void kernel_launch(void* const* d_in, const int* in_sizes, int n_in,
                              void* d_out, int out_size, void* d_ws, size_t ws_size,
                              hipStream_t stream) {
    const float* h    = (const float*)d_in[0];
    const float* pos  = (const float*)d_in[1];
    const float* nrm  = (const float*)d_in[2];
    const float* emb  = (const float*)d_in[3];
    const float* Whp  = (const float*)d_in[4];
    const float* bhp  = (const float*)d_in[5];
    const float* Wn   = (const float*)d_in[6];
    const float* Lw   = (const float*)d_in[7];
    const float* Ew   = (const float*)d_in[8];
    const float* Lwp  = (const float*)d_in[9];
    const float* Ewp  = (const float*)d_in[10];
    const int* esrc   = (const int*)d_in[11];
    const int* edst   = (const int*)d_in[12];
    const int* etyp   = (const int*)d_in[13];

    const int N = in_sizes[2];
    const int E = in_sizes[11];

    float* out  = (float*)d_out;
    float* accb = out;  // acc lives in out's node region until k_final consumes it

    const size_t tBytes  = (size_t)N * 128 * 4;
    const size_t rpBytes = (size_t)N * 4;
    const size_t epBytes = (size_t)E * 4;

    char* wsb = (char*)d_ws;
    float*    t     = (float*)wsb;
    int*      rp    = (int*)(wsb + tBytes);
    unsigned* epack = (unsigned*)(wsb + tBytes + rpBytes);

    const int nblk = (N + 63) / 64;

    if (ws_size >= tBytes + rpBytes + epBytes && N <= 65536 && E > 0) {
        // CSR path: no float atomics
        hipMemsetAsync(rp, 0, rpBytes, stream);
        k_t<<<nblk, 256, 0, stream>>>(h, pos, Whp, t, N);
        k_hist<<<1024, 256, 0, stream>>>(edst, rp, E);
        k_scan<<<1, 1024, 0, stream>>>(rp, N);
        k_scatter<<<1024, 256, 0, stream>>>(esrc, edst, etyp, rp, epack, E);
        k_gather<<<(N + 3) / 4, 256, 0, stream>>>(t, emb, epack, rp, accb, N);
        k_final<<<nblk, 256, 0, stream>>>(h, pos, nrm, bhp, Wn, Lw, Ew, Lwp, Ewp,
                                          accb, rp, nullptr, out, N);
    } else {
        // fallback: atomic scatter
        int* deg = rp;
        hipMemsetAsync(accb, 0, tBytes, stream);
        hipMemsetAsync(deg, 0, rpBytes, stream);
        k_t<<<nblk, 256, 0, stream>>>(h, pos, Whp, t, N);
        k_edge<<<4096, 256, 0, stream>>>(t, emb, esrc, edst, etyp, accb, deg, E);
        k_final<<<nblk, 256, 0, stream>>>(h, pos, nrm, bhp, Wn, Lw, Ew, Lwp, Ewp,
                                          accb, nullptr, deg, out, N);
    }
}

// Round 3
// 233.110 us; speedup vs baseline: 5.2378x; 1.3172x over previous
//
#include <hip/hip_runtime.h>

// UnionRGCNLayer, MFMA-restructured:
//   t[u]   = [h[u] | pos[u]] @ W_hp             (bf16 MFMA + fp32 pos-tail, node-level)
//   x0[v]  = norm[v]*(sum_{e:dst=v}(t[src]+emb[type]) + deg[v]*b_hp)   (CSR gather)
//   out    = relu([x0 | f*h | (1-f)*h] @ [Wn;Lw;Ew])  (bf16 MFMA, f = deg>0)
//   out_pos= relu(pos + pos @ (f ? Lwp : Ewp))
// MFMA packing convention (consistent for A and B; k-permutation cancels):
//   A: lane l elem j -> A[l&15][(l>>4)*8+j];  B: lane l elem j -> B[(l>>4)*8+j][l&15]
//   C/D (m89-verified): lane l reg r -> D[(l>>4)*4+r][l&15]

typedef __bf16 bf16x8 __attribute__((ext_vector_type(8)));
typedef float f32x4 __attribute__((ext_vector_type(4)));
typedef unsigned short u16x4 __attribute__((ext_vector_type(4)));
typedef unsigned short u16x8 __attribute__((ext_vector_type(8)));

__device__ inline unsigned short f2bf(float f) {
    unsigned u = __float_as_uint(f);
    u += 0x7fffu + ((u >> 16) & 1u);
    return (unsigned short)(u >> 16);
}
__device__ inline float bflo(unsigned u) { return __uint_as_float(u << 16); }
__device__ inline float bfhi(unsigned u) { return __uint_as_float(u & 0xffff0000u); }

// ---------------- prep: degree hist + bf16/fragment packing ----------------
__global__ __launch_bounds__(256) void k_prep(const int* __restrict__ dst, int E,
                                              const float* __restrict__ emb, int embN,
                                              const float* __restrict__ Wn,
                                              const float* __restrict__ Lw,
                                              const float* __restrict__ Ew,
                                              const float* __restrict__ Whp,
                                              int* __restrict__ rp,
                                              unsigned short* __restrict__ emb16,
                                              unsigned short* __restrict__ Wfrag,
                                              unsigned short* __restrict__ Whpfrag) {
    const int gid = blockIdx.x * blockDim.x + threadIdx.x;
    const int gs = gridDim.x * blockDim.x;
    for (int i = gid; i < E; i += gs) atomicAdd(&rp[dst[i]], 1);
    for (int i = gid; i < embN; i += gs) emb16[i] = f2bf(emb[i]);
    for (int i = gid; i < 49152; i += gs) {  // [Wn;Lw;Ew] -> fragment order, 12 chunks of K=32
        int j = i & 7, l = (i >> 3) & 63, nt = (i >> 9) & 7, c = i >> 12;
        int k = c * 32 + ((l >> 4) << 3) + j;
        int n = nt * 16 + (l & 15);
        float v = (k < 128) ? Wn[k * 128 + n]
                : (k < 256) ? Lw[(k - 128) * 128 + n]
                            : Ew[(k - 256) * 128 + n];
        Wfrag[i] = f2bf(v);
    }
    for (int i = gid; i < 16384; i += gs) {  // Whp rows 0..127 -> fragment order, 4 chunks
        int j = i & 7, l = (i >> 3) & 63, nt = (i >> 9) & 7, c = i >> 12;
        int k = c * 32 + ((l >> 4) << 3) + j;
        int n = nt * 16 + (l & 15);
        Whpfrag[i] = f2bf(Whp[k * 128 + n]);
    }
}

// ---------------- t = [h|pos] @ W_hp, bf16 MFMA, M-tile=32 ----------------
__global__ __launch_bounds__(256) void k_t(const float* __restrict__ h,
                                           const float* __restrict__ pos,
                                           const float* __restrict__ Whp,
                                           const unsigned short* __restrict__ Whpfrag,
                                           unsigned short* __restrict__ t, int N) {
    __shared__ unsigned short Xs[32][40];
    __shared__ float WpS[3][128];
    __shared__ float posS[32][4];
    const int tid = threadIdx.x;
    const int rbase = blockIdx.x * 32;
    const int w = tid >> 6, l = tid & 63;
    for (int i = tid; i < 384; i += 256) WpS[i >> 7][i & 127] = Whp[128 * 128 + i];
    if (tid < 96) {
        int r = tid / 3, j = tid % 3;
        int row = rbase + r;
        posS[r][j] = (row < N) ? pos[(size_t)row * 3 + j] : 0.f;
    }
    f32x4 acc[4];
#pragma unroll
    for (int i = 0; i < 4; i++) acc[i] = (f32x4){0.f, 0.f, 0.f, 0.f};

    const int rt = w >> 1, ch = w & 1;
    for (int c = 0; c < 4; c++) {
        __syncthreads();
        {
            int r = tid >> 3, kq = tid & 7;
            int row = rbase + r;
            u16x4 v = {0, 0, 0, 0};
            if (row < N) {
                float4 a = *reinterpret_cast<const float4*>(h + (size_t)row * 128 + c * 32 + kq * 4);
                v[0] = f2bf(a.x); v[1] = f2bf(a.y); v[2] = f2bf(a.z); v[3] = f2bf(a.w);
            }
            *reinterpret_cast<u16x4*>(&Xs[r][kq * 4]) = v;
        }
        __syncthreads();
        bf16x8 a = *reinterpret_cast<const bf16x8*>(&Xs[rt * 16 + (l & 15)][(l >> 4) * 8]);
        const bf16x8* Bp = reinterpret_cast<const bf16x8*>(Whpfrag) + (size_t)c * 512;
#pragma unroll
        for (int n2 = 0; n2 < 4; n2++) {
            bf16x8 b = Bp[(ch * 4 + n2) * 64 + l];
            acc[n2] = __builtin_amdgcn_mfma_f32_16x16x32_bf16(a, b, acc[n2], 0, 0, 0);
        }
    }
    const int lrow0 = rt * 16 + ((l >> 4) << 2);
#pragma unroll
    for (int n2 = 0; n2 < 4; n2++) {
        int col = (ch * 4 + n2) * 16 + (l & 15);
        float w0 = WpS[0][col], w1 = WpS[1][col], w2 = WpS[2][col];
#pragma unroll
        for (int r = 0; r < 4; r++) {
            int lr = lrow0 + r;
            int grow = rbase + lr;
            if (grow < N) {
                float v = acc[n2][r] + posS[lr][0] * w0 + posS[lr][1] * w1 + posS[lr][2] * w2;
                t[(size_t)grow * 128 + col] = f2bf(v);
            }
        }
    }
}

// ---------------- CSR scan + scatter ----------------
__global__ __launch_bounds__(1024) void k_scan(int* __restrict__ rp, int N) {
    __shared__ int part[1024];
    const int tid = threadIdx.x;
    const int chunk = (N + 1023) / 1024;
    const int beg = tid * chunk;
    const int end = min(beg + chunk, N);
    int s = 0;
    for (int i = beg; i < end; i++) s += rp[i];
    part[tid] = s;
    __syncthreads();
    for (int off = 1; off < 1024; off <<= 1) {
        int other = (tid >= off) ? part[tid - off] : 0;
        __syncthreads();
        part[tid] += other;
        __syncthreads();
    }
    int running = part[tid] - s;
    for (int i = beg; i < end; i++) {
        int tmp = rp[i];
        rp[i] = running;
        running += tmp;
    }
}

__global__ __launch_bounds__(256) void k_scatter(const int* __restrict__ src,
                                                 const int* __restrict__ dst,
                                                 const int* __restrict__ typ,
                                                 int* __restrict__ rp,
                                                 unsigned* __restrict__ epack, int E) {
    int i = blockIdx.x * blockDim.x + threadIdx.x;
    int stride = gridDim.x * blockDim.x;
    for (int e = i; e < E; e += stride) {
        int d = dst[e];
        int pos = atomicAdd(&rp[d], 1);
        epack[pos] = (unsigned)src[e] | ((unsigned)typ[e] << 16);
    }
}

// ---------------- gather: x0[v] = norm*(sum(t+emb) + deg*b) (fp32 out) ----------------
__global__ __launch_bounds__(256) void k_gather(const unsigned short* __restrict__ t,
                                                const unsigned short* __restrict__ emb16,
                                                const unsigned* __restrict__ epack,
                                                const int* __restrict__ rp,
                                                const float* __restrict__ nrm,
                                                const float* __restrict__ bhp,
                                                float* __restrict__ x0, int N) {
    __shared__ float bsh[128];
    const int tid = threadIdx.x;
    if (tid < 128) bsh[tid] = bhp[tid];
    __syncthreads();
    const int v = (blockIdx.x * blockDim.x + tid) >> 6;
    const int lane = tid & 63;
    if (v >= N) return;
    const int start = v ? rp[v - 1] : 0;
    const int end = rp[v];
    float a0 = 0.f, a1 = 0.f;
    for (int i = start; i < end; i++) {
        unsigned p = epack[i];
        unsigned s = p & 0xffffu;
        unsigned r = p >> 16;
        unsigned tv = *reinterpret_cast<const unsigned*>(t + (size_t)s * 128 + lane * 2);
        unsigned ev = *reinterpret_cast<const unsigned*>(emb16 + (size_t)r * 128 + lane * 2);
        a0 += bflo(tv) + bflo(ev);
        a1 += bfhi(tv) + bfhi(ev);
    }
    float dg = (float)(end - start);
    float nf = nrm[v];
    float r0 = nf * (a0 + dg * bsh[lane * 2]);
    float r1 = nf * (a1 + dg * bsh[lane * 2 + 1]);
    *reinterpret_cast<float2*>(x0 + (size_t)v * 128 + lane * 2) = make_float2(r0, r1);
}

// ---------------- final: out = relu([x0|f*h|(1-f)*h] @ Wfrag), bf16 MFMA ----------------
__global__ __launch_bounds__(256) void k_final(const float* __restrict__ h,
                                               const float* __restrict__ pos,
                                               const float* __restrict__ x0,
                                               const unsigned short* __restrict__ Wfrag,
                                               const float* __restrict__ Lwp,
                                               const float* __restrict__ Ewp,
                                               const int* __restrict__ rp,
                                               float* __restrict__ out, int N) {
    __shared__ unsigned short Xs[32][40];
    __shared__ int flagS[32];
    const int tid = threadIdx.x;
    const int rbase = blockIdx.x * 32;
    const int w = tid >> 6, l = tid & 63;
    if (tid < 32) {
        int row = rbase + tid;
        int dg = 0;
        if (row < N) dg = rp[row] - (row ? rp[row - 1] : 0);
        flagS[tid] = dg > 0;
    }
    f32x4 acc[4];
#pragma unroll
    for (int i = 0; i < 4; i++) acc[i] = (f32x4){0.f, 0.f, 0.f, 0.f};

    const int rt = w >> 1, ch = w & 1;
    for (int c = 0; c < 12; c++) {
        __syncthreads();
        {
            int r = tid >> 3, kq = tid & 7;
            int row = rbase + r;
            int part = c >> 2;
            int kl = (c & 3) * 32 + kq * 4;
            u16x4 v = {0, 0, 0, 0};
            if (row < N) {
                if (part == 0) {
                    float4 a = *reinterpret_cast<const float4*>(x0 + (size_t)row * 128 + kl);
                    v[0] = f2bf(a.x); v[1] = f2bf(a.y); v[2] = f2bf(a.z); v[3] = f2bf(a.w);
                } else {
                    bool keep = (part == 1) ? (flagS[r] != 0) : (flagS[r] == 0);
                    if (keep) {
                        float4 a = *reinterpret_cast<const float4*>(h + (size_t)row * 128 + kl);
                        v[0] = f2bf(a.x); v[1] = f2bf(a.y); v[2] = f2bf(a.z); v[3] = f2bf(a.w);
                    }
                }
            }
            *reinterpret_cast<u16x4*>(&Xs[r][kq * 4]) = v;
        }
        __syncthreads();
        bf16x8 a = *reinterpret_cast<const bf16x8*>(&Xs[rt * 16 + (l & 15)][(l >> 4) * 8]);
        const bf16x8* Bp = reinterpret_cast<const bf16x8*>(Wfrag) + (size_t)c * 512;
#pragma unroll
        for (int n2 = 0; n2 < 4; n2++) {
            bf16x8 b = Bp[(ch * 4 + n2) * 64 + l];
            acc[n2] = __builtin_amdgcn_mfma_f32_16x16x32_bf16(a, b, acc[n2], 0, 0, 0);
        }
    }
    const int lrow0 = rt * 16 + ((l >> 4) << 2);
#pragma unroll
    for (int n2 = 0; n2 < 4; n2++) {
        int col = (ch * 4 + n2) * 16 + (l & 15);
#pragma unroll
        for (int r = 0; r < 4; r++) {
            int grow = rbase + lrow0 + r;
            if (grow < N)
                out[(size_t)grow * 128 + col] = fmaxf(acc[n2][r], 0.f);
        }
    }
    // pos path
    if (tid < 32) {
        int row = rbase + tid;
        if (row < N) {
            float p0 = pos[(size_t)row * 3 + 0];
            float p1 = pos[(size_t)row * 3 + 1];
            float p2 = pos[(size_t)row * 3 + 2];
            const float* M = flagS[tid] ? Lwp : Ewp;
            float o0 = p0 + (p0 * M[0] + p1 * M[3] + p2 * M[6]);
            float o1 = p1 + (p0 * M[1] + p1 * M[4] + p2 * M[7]);
            float o2 = p2 + (p0 * M[2] + p1 * M[5] + p2 * M[8]);
            size_t base = (size_t)N * 128 + (size_t)row * 3;
            out[base + 0] = fmaxf(o0, 0.f);
            out[base + 1] = fmaxf(o1, 0.f);
            out[base + 2] = fmaxf(o2, 0.f);
        }
    }
}

extern "C" void kernel_launch(void* const* d_in, const int* in_sizes, int n_in,
                              void* d_out, int out_size, void* d_ws, size_t ws_size,
                              hipStream_t stream) {
    const float* h   = (const float*)d_in[0];
    const float* pos = (const float*)d_in[1];
    const float* nrm = (const float*)d_in[2];
    const float* emb = (const float*)d_in[3];
    const float* Whp = (const float*)d_in[4];
    const float* bhp = (const float*)d_in[5];
    const float* Wn  = (const float*)d_in[6];
    const float* Lw  = (const float*)d_in[7];
    const float* Ew  = (const float*)d_in[8];
    const float* Lwp = (const float*)d_in[9];
    const float* Ewp = (const float*)d_in[10];
    const int* esrc  = (const int*)d_in[11];
    const int* edst  = (const int*)d_in[12];
    const int* etyp  = (const int*)d_in[13];

    const int N = in_sizes[2];
    const int E = in_sizes[11];
    const int embN = in_sizes[3];

    float* out = (float*)d_out;
    float* x0  = out;  // fp32 aggregate lives in out's node region until k_final

    char* wsb = (char*)d_ws;
    size_t off = 0;
    auto nalloc = [&](size_t bytes) { char* p = wsb + off; off += (bytes + 255) & ~(size_t)255; return p; };
    unsigned short* t       = (unsigned short*)nalloc((size_t)N * 128 * 2);
    int*            rp      = (int*)nalloc((size_t)N * 4);
    unsigned*       epack   = (unsigned*)nalloc((size_t)E * 4);
    unsigned short* emb16   = (unsigned short*)nalloc((size_t)embN * 2);
    unsigned short* Wfrag   = (unsigned short*)nalloc(49152 * 2);
    unsigned short* Whpfrag = (unsigned short*)nalloc(16384 * 2);

    hipMemsetAsync(rp, 0, (size_t)N * 4, stream);
    k_prep<<<1024, 256, 0, stream>>>(edst, E, emb, embN, Wn, Lw, Ew, Whp,
                                     rp, emb16, Wfrag, Whpfrag);
    const int nblk = (N + 31) / 32;
    k_t<<<nblk, 256, 0, stream>>>(h, pos, Whp, Whpfrag, t, N);
    k_scan<<<1, 1024, 0, stream>>>(rp, N);
    k_scatter<<<1024, 256, 0, stream>>>(esrc, edst, etyp, rp, epack, E);
    k_gather<<<(N + 3) / 4, 256, 0, stream>>>(t, emb16, epack, rp, nrm, bhp, x0, N);
    k_final<<<nblk, 256, 0, stream>>>(h, pos, x0, Wfrag, Lwp, Ewp, rp, out, N);
}

// Round 4
// 135.718 us; speedup vs baseline: 8.9966x; 1.7176x over previous
//
#include <hip/hip_runtime.h>

// UnionRGCNLayer, fused MFMA version:
//   t[u]    = [h[u] | pos[u]] @ W_hp                         (bf16 MFMA, node-level)
//   slots: epack[d*64 + pos] = src|type<<16 (atomic slot alloc, overflow side-list)
//   k_fused per 32-row block:
//     phase1: x0[v] = norm*(sum_slots(t[src]+emb[type]) + deg*b)  -> LDS (bf16)
//     phase2: out = relu([x0 | f*h | (1-f)*h] @ [Wn;Lw;Ew])   (bf16 MFMA from LDS)
//     pos:    out_pos = relu(pos + pos @ (f ? Lwp : Ewp))
// MFMA packing convention (consistent A/B; k-permutation cancels):
//   A: lane l elem j -> A[l&15][(l>>4)*8+j];  B: lane l elem j -> B[(l>>4)*8+j][l&15]
//   C/D (m89-verified): lane l reg r -> D[(l>>4)*4+r][l&15]

#define CAP 64
#define OVF_MAX 4096

typedef __bf16 bf16x8 __attribute__((ext_vector_type(8)));
typedef float f32x4 __attribute__((ext_vector_type(4)));
typedef unsigned short u16x4 __attribute__((ext_vector_type(4)));

__device__ inline unsigned short f2bf(float f) {
    unsigned u = __float_as_uint(f);
    u += 0x7fffu + ((u >> 16) & 1u);
    return (unsigned short)(u >> 16);
}
__device__ inline float bflo(unsigned u) { return __uint_as_float(u << 16); }
__device__ inline float bfhi(unsigned u) { return __uint_as_float(u & 0xffff0000u); }

// ---------------- prep: slot-fill + bf16/fragment packing ----------------
__global__ __launch_bounds__(256) void k_prep(const int* __restrict__ src,
                                              const int* __restrict__ dst,
                                              const int* __restrict__ typ, int E,
                                              const float* __restrict__ emb, int embN,
                                              const float* __restrict__ Wn,
                                              const float* __restrict__ Lw,
                                              const float* __restrict__ Ew,
                                              const float* __restrict__ Whp,
                                              int* __restrict__ cnt,
                                              int* __restrict__ ovfc,
                                              uint2* __restrict__ ovf,
                                              unsigned* __restrict__ epack,
                                              unsigned short* __restrict__ emb16,
                                              unsigned short* __restrict__ Wfrag,
                                              unsigned short* __restrict__ Whpfrag) {
    const int gid = blockIdx.x * blockDim.x + threadIdx.x;
    const int gs = gridDim.x * blockDim.x;
    for (int i = gid; i < E; i += gs) {
        int d = dst[i];
        unsigned pk = (unsigned)src[i] | ((unsigned)typ[i] << 16);
        int pos = atomicAdd(&cnt[d], 1);
        if (pos < CAP) {
            epack[(size_t)d * CAP + pos] = pk;
        } else {
            int o = atomicAdd(ovfc, 1);
            if (o < OVF_MAX) ovf[o] = make_uint2((unsigned)d, pk);
        }
    }
    for (int i = gid; i < embN; i += gs) emb16[i] = f2bf(emb[i]);
    for (int i = gid; i < 49152; i += gs) {  // [Wn;Lw;Ew] -> fragment order, 12 chunks of K=32
        int j = i & 7, l = (i >> 3) & 63, nt = (i >> 9) & 7, c = i >> 12;
        int k = c * 32 + ((l >> 4) << 3) + j;
        int n = nt * 16 + (l & 15);
        float v = (k < 128) ? Wn[k * 128 + n]
                : (k < 256) ? Lw[(k - 128) * 128 + n]
                            : Ew[(k - 256) * 128 + n];
        Wfrag[i] = f2bf(v);
    }
    for (int i = gid; i < 16384; i += gs) {  // Whp rows 0..127 -> fragment order, 4 chunks
        int j = i & 7, l = (i >> 3) & 63, nt = (i >> 9) & 7, c = i >> 12;
        int k = c * 32 + ((l >> 4) << 3) + j;
        int n = nt * 16 + (l & 15);
        Whpfrag[i] = f2bf(Whp[k * 128 + n]);
    }
}

// ---------------- t = [h|pos] @ W_hp, bf16 MFMA, M-tile=32 ----------------
__global__ __launch_bounds__(256) void k_t(const float* __restrict__ h,
                                           const float* __restrict__ pos,
                                           const float* __restrict__ Whp,
                                           const unsigned short* __restrict__ Whpfrag,
                                           unsigned short* __restrict__ t, int N) {
    __shared__ unsigned short hsh[32][136];
    __shared__ float WpS[3][128];
    __shared__ float posS[32][4];
    const int tid = threadIdx.x;
    const int rbase = blockIdx.x * 32;
    const int w = tid >> 6, l = tid & 63;
    for (int i = tid; i < 384; i += 256) WpS[i >> 7][i & 127] = Whp[128 * 128 + i];
    if (tid < 96) {
        int r = tid / 3, j = tid % 3;
        int row = rbase + r;
        posS[r][j] = (row < N) ? pos[(size_t)row * 3 + j] : 0.f;
    }
#pragma unroll
    for (int it = 0; it < 4; it++) {  // stage 32x128 h tile as bf16
        int qid = tid + it * 256;
        int rr = qid >> 5, cq = qid & 31;
        int row = rbase + rr;
        u16x4 v = {0, 0, 0, 0};
        if (row < N) {
            float4 a = *reinterpret_cast<const float4*>(h + (size_t)row * 128 + cq * 4);
            v[0] = f2bf(a.x); v[1] = f2bf(a.y); v[2] = f2bf(a.z); v[3] = f2bf(a.w);
        }
        *reinterpret_cast<u16x4*>(&hsh[rr][cq * 4]) = v;
    }
    __syncthreads();

    f32x4 acc[4];
#pragma unroll
    for (int i = 0; i < 4; i++) acc[i] = (f32x4){0.f, 0.f, 0.f, 0.f};
    const int rt = w >> 1, ch = w & 1;
#pragma unroll
    for (int c = 0; c < 4; c++) {
        bf16x8 a = *reinterpret_cast<const bf16x8*>(&hsh[rt * 16 + (l & 15)][c * 32 + (l >> 4) * 8]);
        const bf16x8* Bp = reinterpret_cast<const bf16x8*>(Whpfrag) + (size_t)c * 512;
#pragma unroll
        for (int n2 = 0; n2 < 4; n2++) {
            bf16x8 b = Bp[(ch * 4 + n2) * 64 + l];
            acc[n2] = __builtin_amdgcn_mfma_f32_16x16x32_bf16(a, b, acc[n2], 0, 0, 0);
        }
    }
    const int lrow0 = rt * 16 + ((l >> 4) << 2);
#pragma unroll
    for (int n2 = 0; n2 < 4; n2++) {
        int col = (ch * 4 + n2) * 16 + (l & 15);
        float w0 = WpS[0][col], w1 = WpS[1][col], w2 = WpS[2][col];
#pragma unroll
        for (int r = 0; r < 4; r++) {
            int lr = lrow0 + r;
            int grow = rbase + lr;
            if (grow < N) {
                float v = acc[n2][r] + posS[lr][0] * w0 + posS[lr][1] * w1 + posS[lr][2] * w2;
                t[(size_t)grow * 128 + col] = f2bf(v);
            }
        }
    }
}

// ---------------- fused gather + final GEMM + pos path ----------------
__global__ __launch_bounds__(256) void k_fused(const float* __restrict__ h,
                                               const float* __restrict__ pos,
                                               const float* __restrict__ nrm,
                                               const float* __restrict__ bhp,
                                               const unsigned short* __restrict__ t,
                                               const unsigned short* __restrict__ emb16,
                                               const unsigned* __restrict__ epack,
                                               const int* __restrict__ cnt,
                                               const int* __restrict__ ovfc,
                                               const uint2* __restrict__ ovf,
                                               const unsigned short* __restrict__ Wfrag,
                                               const float* __restrict__ Lwp,
                                               const float* __restrict__ Ewp,
                                               float* __restrict__ out, int N) {
    __shared__ unsigned short x0sh[32][136];
    __shared__ unsigned short hsh[32][136];
    __shared__ int flagS[32];
    const int tid = threadIdx.x;
    const int rbase = blockIdx.x * 32;
    const int w = tid >> 6, lane = tid & 63;

    // issue h-tile loads early (latency hides under phase 1)
    float4 hv[4];
#pragma unroll
    for (int it = 0; it < 4; it++) {
        int qid = tid + it * 256;
        int rr = qid >> 5, cq = qid & 31;
        int row = rbase + rr;
        hv[it] = make_float4(0.f, 0.f, 0.f, 0.f);
        if (row < N)
            hv[it] = *reinterpret_cast<const float4*>(h + (size_t)row * 128 + cq * 4);
    }

    const float b0 = bhp[lane * 2];
    const float b1 = bhp[lane * 2 + 1];
    const unsigned* tw = reinterpret_cast<const unsigned*>(t);
    const unsigned* ew = reinterpret_cast<const unsigned*>(emb16);

    // phase 1: gather x0 for this block's 32 rows (each wave: 8 nodes)
#pragma unroll 1
    for (int q = 0; q < 8; q++) {
        const int vl = w * 8 + q;
        const int v = rbase + vl;
        float a0 = 0.f, a1 = 0.f;
        int dg = 0;
        if (v < N) {
            dg = cnt[v];
            int m = min(dg, CAP);
            const unsigned* ep = epack + (size_t)v * CAP;
            int j = 0;
            for (; j + 8 <= m; j += 8) {
                unsigned pk[8], tvv[8], evv[8];
#pragma unroll
                for (int u = 0; u < 8; u++) pk[u] = ep[j + u];
#pragma unroll
                for (int u = 0; u < 8; u++) tvv[u] = tw[(size_t)(pk[u] & 0xffffu) * 64 + lane];
#pragma unroll
                for (int u = 0; u < 8; u++) evv[u] = ew[(size_t)(pk[u] >> 16) * 64 + lane];
#pragma unroll
                for (int u = 0; u < 8; u++) {
                    a0 += bflo(tvv[u]) + bflo(evv[u]);
                    a1 += bfhi(tvv[u]) + bfhi(evv[u]);
                }
            }
            for (; j < m; j++) {
                unsigned p = ep[j];
                unsigned tv = tw[(size_t)(p & 0xffffu) * 64 + lane];
                unsigned ev = ew[(size_t)(p >> 16) * 64 + lane];
                a0 += bflo(tv) + bflo(ev);
                a1 += bfhi(tv) + bfhi(ev);
            }
            int no = min(ovfc[0], OVF_MAX);  // expected 0
            for (int oj = 0; oj < no; oj++) {
                uint2 o = ovf[oj];
                if ((int)o.x == v) {
                    unsigned tv = tw[(size_t)(o.y & 0xffffu) * 64 + lane];
                    unsigned ev = ew[(size_t)(o.y >> 16) * 64 + lane];
                    a0 += bflo(tv) + bflo(ev);
                    a1 += bfhi(tv) + bfhi(ev);
                }
            }
            float nf = nrm[v];
            a0 = nf * (a0 + (float)dg * b0);
            a1 = nf * (a1 + (float)dg * b1);
        }
        x0sh[vl][lane * 2] = f2bf(a0);
        x0sh[vl][lane * 2 + 1] = f2bf(a1);
        if (lane == 0) flagS[vl] = (dg > 0);
    }

    // write staged h tile (bf16)
#pragma unroll
    for (int it = 0; it < 4; it++) {
        int qid = tid + it * 256;
        int rr = qid >> 5, cq = qid & 31;
        u16x4 v;
        v[0] = f2bf(hv[it].x); v[1] = f2bf(hv[it].y);
        v[2] = f2bf(hv[it].z); v[3] = f2bf(hv[it].w);
        *reinterpret_cast<u16x4*>(&hsh[rr][cq * 4]) = v;
    }
    __syncthreads();

    // phase 2: out = relu([x0 | f*h | (1-f)*h] @ Wfrag)
    f32x4 acc[4];
#pragma unroll
    for (int i = 0; i < 4; i++) acc[i] = (f32x4){0.f, 0.f, 0.f, 0.f};
    const int rt = w >> 1, ch = w & 1;
    const int arow = rt * 16 + (lane & 15);
    const bool fl = (flagS[arow] != 0);
#pragma unroll
    for (int c = 0; c < 12; c++) {
        uint4 raw;
        if (c < 4) {
            raw = *reinterpret_cast<const uint4*>(&x0sh[arow][c * 32 + (lane >> 4) * 8]);
        } else {
            raw = *reinterpret_cast<const uint4*>(&hsh[arow][(c & 3) * 32 + (lane >> 4) * 8]);
            bool keep = (c < 8) ? fl : !fl;
            if (!keep) { raw.x = 0; raw.y = 0; raw.z = 0; raw.w = 0; }
        }
        bf16x8 a = *reinterpret_cast<bf16x8*>(&raw);
        const bf16x8* Bp = reinterpret_cast<const bf16x8*>(Wfrag) + (size_t)c * 512;
#pragma unroll
        for (int n2 = 0; n2 < 4; n2++) {
            bf16x8 b = Bp[(ch * 4 + n2) * 64 + lane];
            acc[n2] = __builtin_amdgcn_mfma_f32_16x16x32_bf16(a, b, acc[n2], 0, 0, 0);
        }
    }
    const int lrow0 = rt * 16 + ((lane >> 4) << 2);
#pragma unroll
    for (int n2 = 0; n2 < 4; n2++) {
        int col = (ch * 4 + n2) * 16 + (lane & 15);
#pragma unroll
        for (int r = 0; r < 4; r++) {
            int grow = rbase + lrow0 + r;
            if (grow < N)
                out[(size_t)grow * 128 + col] = fmaxf(acc[n2][r], 0.f);
        }
    }
    // pos path
    if (tid < 32) {
        int row = rbase + tid;
        if (row < N) {
            float p0 = pos[(size_t)row * 3 + 0];
            float p1 = pos[(size_t)row * 3 + 1];
            float p2 = pos[(size_t)row * 3 + 2];
            const float* M = flagS[tid] ? Lwp : Ewp;
            float o0 = p0 + (p0 * M[0] + p1 * M[3] + p2 * M[6]);
            float o1 = p1 + (p0 * M[1] + p1 * M[4] + p2 * M[7]);
            float o2 = p2 + (p0 * M[2] + p1 * M[5] + p2 * M[8]);
            size_t base = (size_t)N * 128 + (size_t)row * 3;
            out[base + 0] = fmaxf(o0, 0.f);
            out[base + 1] = fmaxf(o1, 0.f);
            out[base + 2] = fmaxf(o2, 0.f);
        }
    }
}

extern "C" void kernel_launch(void* const* d_in, const int* in_sizes, int n_in,
                              void* d_out, int out_size, void* d_ws, size_t ws_size,
                              hipStream_t stream) {
    const float* h   = (const float*)d_in[0];
    const float* pos = (const float*)d_in[1];
    const float* nrm = (const float*)d_in[2];
    const float* emb = (const float*)d_in[3];
    const float* Whp = (const float*)d_in[4];
    const float* bhp = (const float*)d_in[5];
    const float* Wn  = (const float*)d_in[6];
    const float* Lw  = (const float*)d_in[7];
    const float* Ew  = (const float*)d_in[8];
    const float* Lwp = (const float*)d_in[9];
    const float* Ewp = (const float*)d_in[10];
    const int* esrc  = (const int*)d_in[11];
    const int* edst  = (const int*)d_in[12];
    const int* etyp  = (const int*)d_in[13];

    const int N = in_sizes[2];
    const int E = in_sizes[11];
    const int embN = in_sizes[3];

    float* out = (float*)d_out;

    char* wsb = (char*)d_ws;
    size_t off = 0;
    auto nalloc = [&](size_t bytes) { char* p = wsb + off; off += (bytes + 255) & ~(size_t)255; return p; };
    unsigned short* t       = (unsigned short*)nalloc((size_t)N * 128 * 2);
    int*            cnt     = (int*)nalloc((size_t)N * 4);
    int*            ovfc    = (int*)nalloc(256);
    uint2*          ovf     = (uint2*)nalloc((size_t)OVF_MAX * 8);
    unsigned*       epack   = (unsigned*)nalloc((size_t)N * CAP * 4);
    unsigned short* emb16   = (unsigned short*)nalloc((size_t)embN * 2);
    unsigned short* Wfrag   = (unsigned short*)nalloc(49152 * 2);
    unsigned short* Whpfrag = (unsigned short*)nalloc(16384 * 2);

    const size_t cntPad = (((size_t)N * 4) + 255) & ~(size_t)255;
    hipMemsetAsync(cnt, 0, cntPad + 256, stream);  // cnt + ovfc (adjacent)

    k_prep<<<2560, 256, 0, stream>>>(esrc, edst, etyp, E, emb, embN, Wn, Lw, Ew, Whp,
                                     cnt, ovfc, ovf, epack, emb16, Wfrag, Whpfrag);
    const int nblk = (N + 31) / 32;
    k_t<<<nblk, 256, 0, stream>>>(h, pos, Whp, Whpfrag, t, N);
    k_fused<<<nblk, 256, 0, stream>>>(h, pos, nrm, bhp, t, emb16, epack, cnt, ovfc, ovf,
                                      Wfrag, Lwp, Ewp, out, N);
}

// Round 5
// 102.916 us; speedup vs baseline: 11.8640x; 1.3187x over previous
//
#include <hip/hip_runtime.h>

// UnionRGCNLayer, fused MFMA version (latency-optimized gather):
//   t[u]    = [h[u] | pos[u]] @ W_hp                         (bf16 MFMA, node-level)
//   slots: epack[d*64 + pos] = src|type<<16 (atomic slot alloc, overflow side-list)
//   k_fused per 32-row block (512 thr):
//     stage:  epack rows -> LDS (bulk, coalesced)
//     phase1: x0[v] = norm*(sum_slots(t[src]+emb[type]) + deg*b) -> LDS bf16
//             2 nodes per wave (lane halves), uint2 row loads, branchless sel-masking
//     phase2: out = relu([x0 | f*h | (1-f)*h] @ [Wn;Lw;Ew])   (bf16 MFMA from LDS)
//     pos:    out_pos = relu(pos + pos @ (f ? Lwp : Ewp))
// MFMA packing convention (consistent A/B; k-permutation cancels):
//   A: lane l elem j -> A[l&15][(l>>4)*8+j];  B: lane l elem j -> B[(l>>4)*8+j][l&15]
//   C/D (m89-verified): lane l reg r -> D[(l>>4)*4+r][l&15]

#define CAP 64
#define OVF_MAX 4096

typedef __bf16 bf16x8 __attribute__((ext_vector_type(8)));
typedef float f32x4 __attribute__((ext_vector_type(4)));
typedef unsigned short u16x4 __attribute__((ext_vector_type(4)));

__device__ inline unsigned short f2bf(float f) {
    unsigned u = __float_as_uint(f);
    u += 0x7fffu + ((u >> 16) & 1u);
    return (unsigned short)(u >> 16);
}
__device__ inline float bflo(unsigned u) { return __uint_as_float(u << 16); }
__device__ inline float bfhi(unsigned u) { return __uint_as_float(u & 0xffff0000u); }

// ---------------- prep: slot-fill + bf16/fragment packing ----------------
__global__ __launch_bounds__(256) void k_prep(const int* __restrict__ src,
                                              const int* __restrict__ dst,
                                              const int* __restrict__ typ, int E,
                                              const float* __restrict__ emb, int embN,
                                              const float* __restrict__ Wn,
                                              const float* __restrict__ Lw,
                                              const float* __restrict__ Ew,
                                              const float* __restrict__ Whp,
                                              int* __restrict__ cnt,
                                              int* __restrict__ ovfc,
                                              uint2* __restrict__ ovf,
                                              unsigned* __restrict__ epack,
                                              unsigned short* __restrict__ emb16,
                                              unsigned short* __restrict__ Wfrag,
                                              unsigned short* __restrict__ Whpfrag) {
    const int gid = blockIdx.x * blockDim.x + threadIdx.x;
    const int gs = gridDim.x * blockDim.x;
    for (int i = gid; i < E; i += gs) {
        int d = dst[i];
        unsigned pk = (unsigned)src[i] | ((unsigned)typ[i] << 16);
        int pos = atomicAdd(&cnt[d], 1);
        if (pos < CAP) {
            epack[(size_t)d * CAP + pos] = pk;
        } else {
            int o = atomicAdd(ovfc, 1);
            if (o < OVF_MAX) ovf[o] = make_uint2((unsigned)d, pk);
        }
    }
    for (int i = gid; i < embN; i += gs) emb16[i] = f2bf(emb[i]);
    for (int i = gid; i < 49152; i += gs) {  // [Wn;Lw;Ew] -> fragment order, 12 chunks of K=32
        int j = i & 7, l = (i >> 3) & 63, nt = (i >> 9) & 7, c = i >> 12;
        int k = c * 32 + ((l >> 4) << 3) + j;
        int n = nt * 16 + (l & 15);
        float v = (k < 128) ? Wn[k * 128 + n]
                : (k < 256) ? Lw[(k - 128) * 128 + n]
                            : Ew[(k - 256) * 128 + n];
        Wfrag[i] = f2bf(v);
    }
    for (int i = gid; i < 16384; i += gs) {  // Whp rows 0..127 -> fragment order, 4 chunks
        int j = i & 7, l = (i >> 3) & 63, nt = (i >> 9) & 7, c = i >> 12;
        int k = c * 32 + ((l >> 4) << 3) + j;
        int n = nt * 16 + (l & 15);
        Whpfrag[i] = f2bf(Whp[k * 128 + n]);
    }
}

// ---------------- t = [h|pos] @ W_hp, bf16 MFMA, M-tile=32 ----------------
__global__ __launch_bounds__(256) void k_t(const float* __restrict__ h,
                                           const float* __restrict__ pos,
                                           const float* __restrict__ Whp,
                                           const unsigned short* __restrict__ Whpfrag,
                                           unsigned short* __restrict__ t, int N) {
    __shared__ unsigned short hsh[32][136];
    __shared__ float WpS[3][128];
    __shared__ float posS[32][4];
    const int tid = threadIdx.x;
    const int rbase = blockIdx.x * 32;
    const int w = tid >> 6, l = tid & 63;
    for (int i = tid; i < 384; i += 256) WpS[i >> 7][i & 127] = Whp[128 * 128 + i];
    if (tid < 96) {
        int r = tid / 3, j = tid % 3;
        int row = rbase + r;
        posS[r][j] = (row < N) ? pos[(size_t)row * 3 + j] : 0.f;
    }
#pragma unroll
    for (int it = 0; it < 4; it++) {  // stage 32x128 h tile as bf16
        int qid = tid + it * 256;
        int rr = qid >> 5, cq = qid & 31;
        int row = rbase + rr;
        u16x4 v = {0, 0, 0, 0};
        if (row < N) {
            float4 a = *reinterpret_cast<const float4*>(h + (size_t)row * 128 + cq * 4);
            v[0] = f2bf(a.x); v[1] = f2bf(a.y); v[2] = f2bf(a.z); v[3] = f2bf(a.w);
        }
        *reinterpret_cast<u16x4*>(&hsh[rr][cq * 4]) = v;
    }
    __syncthreads();

    f32x4 acc[4];
#pragma unroll
    for (int i = 0; i < 4; i++) acc[i] = (f32x4){0.f, 0.f, 0.f, 0.f};
    const int rt = w >> 1, ch = w & 1;
#pragma unroll
    for (int c = 0; c < 4; c++) {
        bf16x8 a = *reinterpret_cast<const bf16x8*>(&hsh[rt * 16 + (l & 15)][c * 32 + (l >> 4) * 8]);
        const bf16x8* Bp = reinterpret_cast<const bf16x8*>(Whpfrag) + (size_t)c * 512;
#pragma unroll
        for (int n2 = 0; n2 < 4; n2++) {
            bf16x8 b = Bp[(ch * 4 + n2) * 64 + l];
            acc[n2] = __builtin_amdgcn_mfma_f32_16x16x32_bf16(a, b, acc[n2], 0, 0, 0);
        }
    }
    const int lrow0 = rt * 16 + ((l >> 4) << 2);
#pragma unroll
    for (int n2 = 0; n2 < 4; n2++) {
        int col = (ch * 4 + n2) * 16 + (l & 15);
        float w0 = WpS[0][col], w1 = WpS[1][col], w2 = WpS[2][col];
#pragma unroll
        for (int r = 0; r < 4; r++) {
            int lr = lrow0 + r;
            int grow = rbase + lr;
            if (grow < N) {
                float v = acc[n2][r] + posS[lr][0] * w0 + posS[lr][1] * w1 + posS[lr][2] * w2;
                t[(size_t)grow * 128 + col] = f2bf(v);
            }
        }
    }
}

// ---------------- fused gather + final GEMM + pos path (512 threads) ----------------
__global__ __launch_bounds__(512) void k_fused(const float* __restrict__ h,
                                               const float* __restrict__ pos,
                                               const float* __restrict__ nrm,
                                               const float* __restrict__ bhp,
                                               const unsigned short* __restrict__ t,
                                               const unsigned short* __restrict__ emb16,
                                               const unsigned* __restrict__ epack,
                                               const int* __restrict__ cnt,
                                               const int* __restrict__ ovfc,
                                               const uint2* __restrict__ ovf,
                                               const unsigned short* __restrict__ Wfrag,
                                               const float* __restrict__ Lwp,
                                               const float* __restrict__ Ewp,
                                               float* __restrict__ out, int N) {
    __shared__ unsigned epsh[32 * CAP];          // 8 KB
    __shared__ unsigned short x0sh[32][136];     // 8.5 KB
    __shared__ unsigned short hsh[32][136];      // 8.5 KB
    __shared__ float bsh[128];
    __shared__ float nrmS[32];
    __shared__ int cntS[32];
    __shared__ int flagS[32];
    const int tid = threadIdx.x;
    const int rbase = blockIdx.x * 32;
    const int w = tid >> 6, lane = tid & 63;
    const int half = lane >> 5, l32 = lane & 31;

    // bulk-stage this block's epack rows into LDS (coalesced)
    {
        uint4 v = *reinterpret_cast<const uint4*>(epack + (size_t)rbase * CAP + tid * 4);
        *reinterpret_cast<uint4*>(&epsh[tid * 4]) = v;
    }
    if (tid < 128) bsh[tid] = bhp[tid];
    if (tid < 32) {
        int row = rbase + tid;
        int dg = (row < N) ? cnt[row] : 0;
        cntS[tid] = dg;
        flagS[tid] = dg > 0;
        nrmS[tid] = (row < N) ? nrm[row] : 0.f;
    }
    __syncthreads();

    const uint2* tw2 = reinterpret_cast<const uint2*>(t);      // row stride 32 (8B elems)
    const uint2* ew2 = reinterpret_cast<const uint2*>(emb16);
    const int no = min(ovfc[0], OVF_MAX);  // expected 0

    // phase 1: 2 nodes per wave (lane halves), branchless sel-masked 8-edge chunks
#pragma unroll 1
    for (int p = 0; p < 2; p++) {
        const int vl = p * 16 + w * 2 + half;
        const int v = rbase + vl;
        const int mh = min(cntS[vl], CAP);
        const int vlA = p * 16 + w * 2;
        const int mmax = max(min(cntS[vlA], CAP), min(cntS[vlA + 1], CAP));  // wave-uniform
        float a0 = 0.f, a1 = 0.f, a2 = 0.f, a3 = 0.f;
        const unsigned* eprow = &epsh[vl * CAP];
#pragma unroll 1
        for (int j = 0; j < mmax; j += 8) {
            unsigned pk[8];
            uint2 tv[8], ev[8];
            float sel[8];
#pragma unroll
            for (int u = 0; u < 8; u++) {
                int idx = j + u;
                unsigned pe = eprow[min(idx, CAP - 1)];
                bool val = idx < mh;
                pk[u] = val ? pe : 0u;      // invalid -> row 0 (always-valid address)
                sel[u] = val ? 1.f : 0.f;
            }
#pragma unroll
            for (int u = 0; u < 8; u++) tv[u] = tw2[(size_t)(pk[u] & 0xffffu) * 32 + l32];
#pragma unroll
            for (int u = 0; u < 8; u++) ev[u] = ew2[(size_t)(pk[u] >> 16) * 32 + l32];
#pragma unroll
            for (int u = 0; u < 8; u++) {
                a0 += sel[u] * (bflo(tv[u].x) + bflo(ev[u].x));
                a1 += sel[u] * (bfhi(tv[u].x) + bfhi(ev[u].x));
                a2 += sel[u] * (bflo(tv[u].y) + bflo(ev[u].y));
                a3 += sel[u] * (bfhi(tv[u].y) + bfhi(ev[u].y));
            }
        }
        // overflow side-list (normally empty)
#pragma unroll 1
        for (int oj = 0; oj < no; oj++) {
            uint2 o = ovf[oj];
            float sel = ((int)o.x == v) ? 1.f : 0.f;
            uint2 tv = tw2[(size_t)(o.y & 0xffffu) * 32 + l32];
            uint2 ev = ew2[(size_t)(o.y >> 16) * 32 + l32];
            a0 += sel * (bflo(tv.x) + bflo(ev.x));
            a1 += sel * (bfhi(tv.x) + bfhi(ev.x));
            a2 += sel * (bflo(tv.y) + bflo(ev.y));
            a3 += sel * (bfhi(tv.y) + bfhi(ev.y));
        }
        float dg = (float)cntS[vl];
        float nf = nrmS[vl];
        u16x4 xo;
        xo[0] = f2bf(nf * (a0 + dg * bsh[l32 * 4 + 0]));
        xo[1] = f2bf(nf * (a1 + dg * bsh[l32 * 4 + 1]));
        xo[2] = f2bf(nf * (a2 + dg * bsh[l32 * 4 + 2]));
        xo[3] = f2bf(nf * (a3 + dg * bsh[l32 * 4 + 3]));
        *reinterpret_cast<u16x4*>(&x0sh[vl][l32 * 4]) = xo;
    }

    // stage h tile as bf16 (2 float4 per thread)
#pragma unroll
    for (int it = 0; it < 2; it++) {
        int qid = tid + it * 512;
        int rr = qid >> 5, cq = qid & 31;
        int row = rbase + rr;
        float4 a = make_float4(0.f, 0.f, 0.f, 0.f);
        if (row < N)
            a = *reinterpret_cast<const float4*>(h + (size_t)row * 128 + cq * 4);
        u16x4 vv;
        vv[0] = f2bf(a.x); vv[1] = f2bf(a.y); vv[2] = f2bf(a.z); vv[3] = f2bf(a.w);
        *reinterpret_cast<u16x4*>(&hsh[rr][cq * 4]) = vv;
    }
    __syncthreads();

    // phase 2: out = relu([x0 | f*h | (1-f)*h] @ Wfrag); 8 waves = 2 row x 4 col tiles
    f32x4 acc[2];
    acc[0] = (f32x4){0.f, 0.f, 0.f, 0.f};
    acc[1] = (f32x4){0.f, 0.f, 0.f, 0.f};
    const int rt = w >> 2, ch = w & 3;
    const int arow = rt * 16 + (lane & 15);
    const bool fl = (flagS[arow] != 0);
#pragma unroll
    for (int c = 0; c < 12; c++) {
        uint4 raw;
        if (c < 4) {
            raw = *reinterpret_cast<const uint4*>(&x0sh[arow][c * 32 + (lane >> 4) * 8]);
        } else {
            raw = *reinterpret_cast<const uint4*>(&hsh[arow][(c & 3) * 32 + (lane >> 4) * 8]);
            bool keep = (c < 8) ? fl : !fl;
            if (!keep) { raw.x = 0; raw.y = 0; raw.z = 0; raw.w = 0; }
        }
        bf16x8 a = *reinterpret_cast<bf16x8*>(&raw);
        const bf16x8* Bp = reinterpret_cast<const bf16x8*>(Wfrag) + (size_t)c * 512;
#pragma unroll
        for (int n2 = 0; n2 < 2; n2++) {
            bf16x8 b = Bp[(ch * 2 + n2) * 64 + lane];
            acc[n2] = __builtin_amdgcn_mfma_f32_16x16x32_bf16(a, b, acc[n2], 0, 0, 0);
        }
    }
    const int lrow0 = rt * 16 + ((lane >> 4) << 2);
#pragma unroll
    for (int n2 = 0; n2 < 2; n2++) {
        int col = (ch * 2 + n2) * 16 + (lane & 15);
#pragma unroll
        for (int r = 0; r < 4; r++) {
            int grow = rbase + lrow0 + r;
            if (grow < N)
                out[(size_t)grow * 128 + col] = fmaxf(acc[n2][r], 0.f);
        }
    }
    // pos path
    if (tid < 32) {
        int row = rbase + tid;
        if (row < N) {
            float p0 = pos[(size_t)row * 3 + 0];
            float p1 = pos[(size_t)row * 3 + 1];
            float p2 = pos[(size_t)row * 3 + 2];
            const float* M = flagS[tid] ? Lwp : Ewp;
            float o0 = p0 + (p0 * M[0] + p1 * M[3] + p2 * M[6]);
            float o1 = p1 + (p0 * M[1] + p1 * M[4] + p2 * M[7]);
            float o2 = p2 + (p0 * M[2] + p1 * M[5] + p2 * M[8]);
            size_t base = (size_t)N * 128 + (size_t)row * 3;
            out[base + 0] = fmaxf(o0, 0.f);
            out[base + 1] = fmaxf(o1, 0.f);
            out[base + 2] = fmaxf(o2, 0.f);
        }
    }
}

extern "C" void kernel_launch(void* const* d_in, const int* in_sizes, int n_in,
                              void* d_out, int out_size, void* d_ws, size_t ws_size,
                              hipStream_t stream) {
    const float* h   = (const float*)d_in[0];
    const float* pos = (const float*)d_in[1];
    const float* nrm = (const float*)d_in[2];
    const float* emb = (const float*)d_in[3];
    const float* Whp = (const float*)d_in[4];
    const float* bhp = (const float*)d_in[5];
    const float* Wn  = (const float*)d_in[6];
    const float* Lw  = (const float*)d_in[7];
    const float* Ew  = (const float*)d_in[8];
    const float* Lwp = (const float*)d_in[9];
    const float* Ewp = (const float*)d_in[10];
    const int* esrc  = (const int*)d_in[11];
    const int* edst  = (const int*)d_in[12];
    const int* etyp  = (const int*)d_in[13];

    const int N = in_sizes[2];
    const int E = in_sizes[11];
    const int embN = in_sizes[3];

    float* out = (float*)d_out;

    char* wsb = (char*)d_ws;
    size_t off = 0;
    auto nalloc = [&](size_t bytes) { char* p = wsb + off; off += (bytes + 255) & ~(size_t)255; return p; };
    unsigned short* t       = (unsigned short*)nalloc((size_t)N * 128 * 2);
    int*            cnt     = (int*)nalloc((size_t)N * 4);
    int*            ovfc    = (int*)nalloc(256);
    uint2*          ovf     = (uint2*)nalloc((size_t)OVF_MAX * 8);
    unsigned*       epack   = (unsigned*)nalloc((size_t)N * CAP * 4);
    unsigned short* emb16   = (unsigned short*)nalloc((size_t)embN * 2);
    unsigned short* Wfrag   = (unsigned short*)nalloc(49152 * 2);
    unsigned short* Whpfrag = (unsigned short*)nalloc(16384 * 2);

    const size_t cntPad = (((size_t)N * 4) + 255) & ~(size_t)255;
    hipMemsetAsync(cnt, 0, cntPad + 256, stream);  // cnt + ovfc (adjacent)

    k_prep<<<2560, 256, 0, stream>>>(esrc, edst, etyp, E, emb, embN, Wn, Lw, Ew, Whp,
                                     cnt, ovfc, ovf, epack, emb16, Wfrag, Whpfrag);
    const int nblk = (N + 31) / 32;
    k_t<<<nblk, 256, 0, stream>>>(h, pos, Whp, Whpfrag, t, N);
    k_fused<<<nblk, 512, 0, stream>>>(h, pos, nrm, bhp, t, emb16, epack, cnt, ovfc, ovf,
                                      Wfrag, Lwp, Ewp, out, N);
}